// Round 2
// baseline (1762.275 us; speedup 1.0000x reference)
//
#include <hip/hip_runtime.h>
#include <math.h>

#define NF 256
#define NH 128
#define NC 16

// ---------------------------------------------------------------------------
// deg[i] = number of real edges with dst == i   (self-loop added later as +1)
__global__ void deg_kernel(const int* __restrict__ dst, int* __restrict__ deg, int E) {
    int e = blockIdx.x * 256 + threadIdx.x;
    if (e < E) atomicAdd(&deg[dst[e]], 1);
}

// dis[i] = rsqrt(deg[i] + 1)   (deg includes self-loop -> always > 0)
__global__ void dis_kernel(const int* __restrict__ deg, float* __restrict__ dis, int N) {
    int i = blockIdx.x * 256 + threadIdx.x;
    if (i < N) dis[i] = rsqrtf((float)(deg[i] + 1));
}

// ---------------------------------------------------------------------------
// h1[N,128] = x[N,256] @ W1[256,128].  Thread computes (row, 4 cols).
// Wave = 2 rows x 32 col-groups: x loads are half-wave-uniform (L1 broadcast),
// W1 float4 loads coalesced; W1 (128KB) stays L2-resident.
__global__ void gemm1_kernel(const float* __restrict__ x, const float* __restrict__ W1,
                             float* __restrict__ h1, int N) {
    int t = blockIdx.x * 256 + threadIdx.x;
    int row = t >> 5;
    if (row >= N) return;
    int cg = (t & 31) << 2;
    const float* xr = x + (size_t)row * NF;
    float4 acc = make_float4(0.f, 0.f, 0.f, 0.f);
#pragma unroll 2
    for (int k = 0; k < NF; k += 4) {
        float4 xv = *reinterpret_cast<const float4*>(xr + k);
        float4 w0 = *reinterpret_cast<const float4*>(W1 + (size_t)(k + 0) * NH + cg);
        float4 w1 = *reinterpret_cast<const float4*>(W1 + (size_t)(k + 1) * NH + cg);
        float4 w2 = *reinterpret_cast<const float4*>(W1 + (size_t)(k + 2) * NH + cg);
        float4 w3 = *reinterpret_cast<const float4*>(W1 + (size_t)(k + 3) * NH + cg);
        acc.x += xv.x * w0.x + xv.y * w1.x + xv.z * w2.x + xv.w * w3.x;
        acc.y += xv.x * w0.y + xv.y * w1.y + xv.z * w2.y + xv.w * w3.y;
        acc.z += xv.x * w0.z + xv.y * w1.z + xv.z * w2.z + xv.w * w3.z;
        acc.w += xv.x * w0.w + xv.y * w1.w + xv.z * w2.w + xv.w * w3.w;
    }
    *reinterpret_cast<float4*>(h1 + (size_t)row * NH + cg) = acc;
}

// ---------------------------------------------------------------------------
// Layer-1 aggregation: one wave per edge, lane handles 2 features (float2).
// src/dst uniform per wave -> gather is one contiguous 512B read of h1[src],
// scatter is 2 atomic instrs whose 64 lanes hit one contiguous 512B region.
__global__ void agg1_kernel(const int* __restrict__ src, const int* __restrict__ dst,
                            const float* __restrict__ dis, const float* __restrict__ h1,
                            float* __restrict__ agg1, int E) {
    int t = blockIdx.x * 256 + threadIdx.x;
    int e = t >> 6;
    if (e >= E) return;
    int lane = t & 63;
    int s = src[e], d = dst[e];
    float norm = dis[s] * dis[d];
    float2 v = *reinterpret_cast<const float2*>(h1 + (size_t)s * NH + lane * 2);
    float* a = agg1 + (size_t)d * NH + lane * 2;
    atomicAdd(a,     v.x * norm);
    atomicAdd(a + 1, v.y * norm);
}

// ---------------------------------------------------------------------------
// out1 = relu(agg1 + dis^2 * h1 + b1), written IN PLACE over h1.
__global__ void relu_kernel(float* __restrict__ h1, const float* __restrict__ agg1,
                            const float* __restrict__ dis, const float* __restrict__ b1,
                            int N) {
    int t = blockIdx.x * 256 + threadIdx.x;
    int i = t >> 5;
    if (i >= N) return;
    int cg = (t & 31) << 2;
    float d2 = dis[i];
    d2 *= d2;
    size_t off = (size_t)i * NH + cg;
    float4 a = *reinterpret_cast<const float4*>(agg1 + off);
    float4 h = *reinterpret_cast<const float4*>(h1 + off);
    float4 b = *reinterpret_cast<const float4*>(b1 + cg);
    float4 r;
    r.x = fmaxf(a.x + d2 * h.x + b.x, 0.f);
    r.y = fmaxf(a.y + d2 * h.y + b.y, 0.f);
    r.z = fmaxf(a.z + d2 * h.z + b.z, 0.f);
    r.w = fmaxf(a.w + d2 * h.w + b.w, 0.f);
    *reinterpret_cast<float4*>(h1 + off) = r;
}

// ---------------------------------------------------------------------------
// h2[N,16] = out1[N,128] @ W2[128,16].  One wave per node; lane c holds
// out1[i][c] and out1[i][c+64]; 16 partial products reduced across the wave.
__global__ void gemm2_kernel(const float* __restrict__ out1, const float* __restrict__ W2,
                             float* __restrict__ h2, int N) {
    int t = blockIdx.x * 256 + threadIdx.x;
    int wid = t >> 6;
    if (wid >= N) return;
    int lane = t & 63;
    float v0 = out1[(size_t)wid * NH + lane];
    float v1 = out1[(size_t)wid * NH + 64 + lane];
    const float* w0 = W2 + (size_t)lane * NC;
    const float* w1 = W2 + (size_t)(64 + lane) * NC;
    float p[NC];
#pragma unroll
    for (int j = 0; j < NC; ++j) p[j] = v0 * w0[j] + v1 * w1[j];
#pragma unroll
    for (int j = 0; j < NC; ++j) {
        float s = p[j];
        for (int m = 32; m > 0; m >>= 1) s += __shfl_xor(s, m, 64);
        p[j] = s;
    }
    // avoid runtime register indexing (scratch): unrolled select
    float outv = 0.f;
#pragma unroll
    for (int j = 0; j < NC; ++j) outv = (lane == j) ? p[j] : outv;
    if (lane < NC) h2[(size_t)wid * NC + lane] = outv;
}

// ---------------------------------------------------------------------------
// Layer-2 aggregation: 16 lanes per edge; contiguous 64B gather + 64B atomic
// region per edge-group.  Accumulates directly into d_out (zeroed first).
__global__ void agg2_kernel(const int* __restrict__ src, const int* __restrict__ dst,
                            const float* __restrict__ dis, const float* __restrict__ h2,
                            float* __restrict__ out, int E) {
    int t = blockIdx.x * 256 + threadIdx.x;
    int e = t >> 4;
    if (e >= E) return;
    int j = t & 15;
    int s = src[e], d = dst[e];
    float norm = dis[s] * dis[d];
    atomicAdd(&out[(size_t)d * NC + j], h2[(size_t)s * NC + j] * norm);
}

// ---------------------------------------------------------------------------
// Final: add self-loop + bias, log_softmax, in place in d_out.
__global__ void final_kernel(float* __restrict__ out, const float* __restrict__ h2,
                             const float* __restrict__ dis, const float* __restrict__ b2,
                             int N) {
    int i = blockIdx.x * 256 + threadIdx.x;
    if (i >= N) return;
    float d2 = dis[i];
    d2 *= d2;
    float l[NC];
    float m = -1e30f;
#pragma unroll
    for (int j = 0; j < NC; ++j) {
        l[j] = out[(size_t)i * NC + j] + d2 * h2[(size_t)i * NC + j] + b2[j];
        m = fmaxf(m, l[j]);
    }
    float ssum = 0.f;
#pragma unroll
    for (int j = 0; j < NC; ++j) ssum += __expf(l[j] - m);
    float lse = m + __logf(ssum);
#pragma unroll
    for (int j = 0; j < NC; ++j) out[(size_t)i * NC + j] = l[j] - lse;
}

// ---------------------------------------------------------------------------
extern "C" void kernel_launch(void* const* d_in, const int* in_sizes, int n_in,
                              void* d_out, int out_size, void* d_ws, size_t ws_size,
                              hipStream_t stream) {
    const float* x  = (const float*)d_in[0];
    const int*   ei = (const int*)d_in[1];
    const float* W1 = (const float*)d_in[2];
    const float* b1 = (const float*)d_in[3];
    const float* W2 = (const float*)d_in[4];
    const float* b2 = (const float*)d_in[5];
    float* out = (float*)d_out;

    const int N = in_sizes[0] / NF;   // 50000
    const int E = in_sizes[1] / 2;    // 1600000
    const int* src = ei;
    const int* dst = ei + E;

    // workspace layout
    float* h1   = (float*)d_ws;                    // N*128
    float* agg1 = h1 + (size_t)N * NH;             // N*128
    float* h2   = agg1 + (size_t)N * NH;           // N*16
    int*   deg  = (int*)(h2 + (size_t)N * NC);     // N
    float* dis  = (float*)(deg + N);               // N

    // per-call init (harness does not re-zero between replays)
    hipMemsetAsync(agg1, 0, (size_t)N * NH * sizeof(float), stream);
    hipMemsetAsync(deg,  0, (size_t)N * sizeof(int), stream);
    hipMemsetAsync(out,  0, (size_t)N * NC * sizeof(float), stream);

    deg_kernel<<<(E + 255) / 256, 256, 0, stream>>>(dst, deg, E);
    dis_kernel<<<(N + 255) / 256, 256, 0, stream>>>(deg, dis, N);

    gemm1_kernel<<<((size_t)N * 32 + 255) / 256, 256, 0, stream>>>(x, W1, h1, N);

    agg1_kernel<<<((size_t)E * 64 + 255) / 256, 256, 0, stream>>>(src, dst, dis, h1, agg1, E);

    relu_kernel<<<((size_t)N * 32 + 255) / 256, 256, 0, stream>>>(h1, agg1, dis, b1, N);

    gemm2_kernel<<<((size_t)N * 64 + 255) / 256, 256, 0, stream>>>(h1, W2, h2, N);

    agg2_kernel<<<((size_t)E * 16 + 255) / 256, 256, 0, stream>>>(src, dst, dis, h2, out, E);

    final_kernel<<<(N + 255) / 256, 256, 0, stream>>>(out, h2, dis, b2, N);
}

// Round 5
// 650.738 us; speedup vs baseline: 2.7081x; 2.7081x over previous
//
#include <hip/hip_runtime.h>
#include <math.h>

#define NF 256
#define NH 128
#define NC 16

// ---- bf16 pack/unpack (RNE) ----------------------------------------------
__device__ __forceinline__ unsigned f2b(float f) {
    unsigned u = __float_as_uint(f);
    return (u + 0x7FFFu + ((u >> 16) & 1u)) >> 16;
}
__device__ __forceinline__ unsigned pack2(float a, float b) {
    return f2b(a) | (f2b(b) << 16);
}
__device__ __forceinline__ float blo(unsigned u) { return __uint_as_float(u << 16); }
__device__ __forceinline__ float bhi(unsigned u) { return __uint_as_float(u & 0xFFFF0000u); }

// ---------------------------------------------------------------------------
// deg[i] = #real edges with dst==i (self-loop folded in later as +1)
__global__ void deg_kernel(const int* __restrict__ dst, int* __restrict__ deg, int E) {
    int e = blockIdx.x * 256 + threadIdx.x;
    if (e < E) atomicAdd(&deg[dst[e]], 1);
}

// ---------------------------------------------------------------------------
// Single-block exclusive scan of deg -> rowptr & cursor; also dis = rsqrt(deg+1).
__global__ void scan_kernel(const int* __restrict__ deg, int* __restrict__ rowptr,
                            int* __restrict__ cursor, float* __restrict__ dis,
                            int N, int E) {
    __shared__ int sm[1024];
    int tid = threadIdx.x;
    int chunk = (N + 1023) >> 10;
    int base = tid * chunk;
    int end = base + chunk; if (end > N) end = N;
    int mysum = 0;
    for (int i = base; i < end; ++i) mysum += deg[i];
    sm[tid] = mysum;
    __syncthreads();
    for (int off = 1; off < 1024; off <<= 1) {
        int v = (tid >= off) ? sm[tid - off] : 0;
        __syncthreads();
        sm[tid] += v;
        __syncthreads();
    }
    int running = sm[tid] - mysum;
    for (int i = base; i < end; ++i) {
        rowptr[i] = running;
        cursor[i] = running;
        dis[i] = rsqrtf((float)(deg[i] + 1));
        running += deg[i];
    }
    if (tid == 0) rowptr[N] = E;
}

// ---------------------------------------------------------------------------
// Bucket edges by dst (slot order nondeterministic -> only fp32 sum order).
__global__ void fill_kernel(const int* __restrict__ src, const int* __restrict__ dst,
                            int* __restrict__ cursor, int* __restrict__ colidx, int E) {
    int e = blockIdx.x * 256 + threadIdx.x;
    if (e < E) {
        int pos = atomicAdd(&cursor[dst[e]], 1);
        colidx[pos] = src[e];
    }
}

// ---------------------------------------------------------------------------
// h1sb[i,:] = bf16( dis[i] * (x[i,:] @ W1) ), packed 2 bf16 per u32 (64 u32/row).
__global__ void gemm1s_kernel(const float* __restrict__ x, const float* __restrict__ W1,
                              const float* __restrict__ dis, unsigned* __restrict__ h1sb,
                              int N) {
    int t = blockIdx.x * 256 + threadIdx.x;
    int row = t >> 5;
    if (row >= N) return;
    int cg = (t & 31) << 2;
    const float* xr = x + (size_t)row * NF;
    float4 acc = make_float4(0.f, 0.f, 0.f, 0.f);
#pragma unroll 2
    for (int k = 0; k < NF; k += 4) {
        float4 xv = *reinterpret_cast<const float4*>(xr + k);
        float4 w0 = *reinterpret_cast<const float4*>(W1 + (size_t)(k + 0) * NH + cg);
        float4 w1 = *reinterpret_cast<const float4*>(W1 + (size_t)(k + 1) * NH + cg);
        float4 w2 = *reinterpret_cast<const float4*>(W1 + (size_t)(k + 2) * NH + cg);
        float4 w3 = *reinterpret_cast<const float4*>(W1 + (size_t)(k + 3) * NH + cg);
        acc.x += xv.x * w0.x + xv.y * w1.x + xv.z * w2.x + xv.w * w3.x;
        acc.y += xv.x * w0.y + xv.y * w1.y + xv.z * w2.y + xv.w * w3.y;
        acc.z += xv.x * w0.z + xv.y * w1.z + xv.z * w2.z + xv.w * w3.z;
        acc.w += xv.x * w0.w + xv.y * w1.w + xv.z * w2.w + xv.w * w3.w;
    }
    float d = dis[row];
    uint2 st;
    st.x = pack2(acc.x * d, acc.y * d);
    st.y = pack2(acc.z * d, acc.w * d);
    *reinterpret_cast<uint2*>(h1sb + (size_t)row * 64 + (cg >> 1)) = st;
}

// ---------------------------------------------------------------------------
// Layer 1 pull + ReLU + GEMM2, fused.  One wave per node (4 nodes/block).
// Gathers are bf16 rows (256B/edge); accumulate fp32; h2sb written bf16-packed.
// N = 50000 = 12500 blocks * 4 waves exactly -> no partial blocks.
__global__ __launch_bounds__(256) void layer1_kernel(
    const int* __restrict__ rowptr, const int* __restrict__ colidx,
    const unsigned* __restrict__ h1sb, const float* __restrict__ dis,
    const float* __restrict__ b1, const float* __restrict__ W2,
    unsigned* __restrict__ h2sb, int N) {
    __shared__ float sW2[NH * NC];   // 8 KB
    __shared__ float srow[4][NH];    // 2 KB
    int tid = threadIdx.x;
    for (int k = tid; k < NH * NC; k += 256) sW2[k] = W2[k];
    __syncthreads();

    int wid = tid >> 6, lane = tid & 63;
    int i = blockIdx.x * 4 + wid;
    if (i >= N) return;
    int e = rowptr[i], e1 = rowptr[i + 1];
    unsigned sv = h1sb[(size_t)i * 64 + lane];          // self-loop
    float accx = blo(sv), accy = bhi(sv);
    for (; e + 4 <= e1; e += 4) {
        int a = colidx[e], b = colidx[e + 1], c = colidx[e + 2], d = colidx[e + 3];
        unsigned va = h1sb[(size_t)a * 64 + lane];
        unsigned vb = h1sb[(size_t)b * 64 + lane];
        unsigned vc = h1sb[(size_t)c * 64 + lane];
        unsigned vd = h1sb[(size_t)d * 64 + lane];
        accx += (blo(va) + blo(vb)) + (blo(vc) + blo(vd));
        accy += (bhi(va) + bhi(vb)) + (bhi(vc) + bhi(vd));
    }
    for (; e < e1; ++e) {
        unsigned v = h1sb[(size_t)colidx[e] * 64 + lane];
        accx += blo(v); accy += bhi(v);
    }
    float di = dis[i];
    int c0 = lane * 2;
    srow[wid][c0]     = fmaxf(di * accx + b1[c0], 0.f);
    srow[wid][c0 + 1] = fmaxf(di * accy + b1[c0 + 1], 0.f);
    // fused GEMM2: lane = q*16+j; partial over c in [q*32, q*32+32)
    int j = lane & 15, q = lane >> 4;
    const float* rw = srow[wid];
    float p = 0.f;
#pragma unroll
    for (int cc = 0; cc < 32; ++cc) {
        int c = q * 32 + cc;
        p += rw[c] * sW2[c * NC + j];
    }
    p += __shfl_xor(p, 16, 64);
    p += __shfl_xor(p, 32, 64);
    float dp = di * p;                       // every lane: full sum for class (lane&15)
    // pack classes (2k, 2k+1) from lanes 2k, 2k+1; lanes 0..7 store row of 8 u32
    float plo = __shfl(dp, (lane << 1) & 63, 64);
    float phi = __shfl(dp, ((lane << 1) | 1) & 63, 64);
    if (lane < 8) h2sb[(size_t)i * 8 + lane] = pack2(plo, phi);
}

// ---------------------------------------------------------------------------
// Layer 2 pull + bias + log_softmax, fused.  8 lanes per node, 32 nodes/block;
// each lane owns 2 classes packed in one u32.
__global__ void layer2_kernel(const int* __restrict__ rowptr, const int* __restrict__ colidx,
                              const unsigned* __restrict__ h2sb, const float* __restrict__ dis,
                              const float* __restrict__ b2, float* __restrict__ out, int N) {
    int t = blockIdx.x * 256 + threadIdx.x;
    int i = t >> 3;
    if (i >= N) return;
    int j2 = t & 7;
    int e = rowptr[i], e1 = rowptr[i + 1];
    unsigned sv = h2sb[(size_t)i * 8 + j2];             // self-loop
    float ax = blo(sv), ay = bhi(sv);
    for (; e + 4 <= e1; e += 4) {
        int a = colidx[e], b = colidx[e + 1], c = colidx[e + 2], d = colidx[e + 3];
        unsigned ga = h2sb[(size_t)a * 8 + j2];
        unsigned gb = h2sb[(size_t)b * 8 + j2];
        unsigned gc = h2sb[(size_t)c * 8 + j2];
        unsigned gd = h2sb[(size_t)d * 8 + j2];
        ax += (blo(ga) + blo(gb)) + (blo(gc) + blo(gd));
        ay += (bhi(ga) + bhi(gb)) + (bhi(gc) + bhi(gd));
    }
    for (; e < e1; ++e) {
        unsigned g = h2sb[(size_t)colidx[e] * 8 + j2];
        ax += blo(g); ay += bhi(g);
    }
    float di = dis[i];
    float l0 = di * ax + b2[2 * j2];
    float l1 = di * ay + b2[2 * j2 + 1];
    float m = fmaxf(l0, l1);
    m = fmaxf(m, __shfl_xor(m, 1, 64));
    m = fmaxf(m, __shfl_xor(m, 2, 64));
    m = fmaxf(m, __shfl_xor(m, 4, 64));
    float s = __expf(l0 - m) + __expf(l1 - m);
    s += __shfl_xor(s, 1, 64);
    s += __shfl_xor(s, 2, 64);
    s += __shfl_xor(s, 4, 64);
    float lse = m + __logf(s);
    float2 o = make_float2(l0 - lse, l1 - lse);
    *reinterpret_cast<float2*>(out + (size_t)i * NC + 2 * j2) = o;
}

// ---------------------------------------------------------------------------
extern "C" void kernel_launch(void* const* d_in, const int* in_sizes, int n_in,
                              void* d_out, int out_size, void* d_ws, size_t ws_size,
                              hipStream_t stream) {
    const float* x  = (const float*)d_in[0];
    const int*   ei = (const int*)d_in[1];
    const float* W1 = (const float*)d_in[2];
    const float* b1 = (const float*)d_in[3];
    const float* W2 = (const float*)d_in[4];
    const float* b2 = (const float*)d_in[5];
    float* out = (float*)d_out;

    const int N = in_sizes[0] / NF;   // 50000
    const int E = in_sizes[1] / 2;    // 1600000
    const int* src = ei;
    const int* dst = ei + E;

    // workspace layout (~22 MB)
    unsigned* h1sb  = (unsigned*)d_ws;                 // N*64 u32 (12.8 MB)
    unsigned* h2sb  = h1sb + (size_t)N * 64;           // N*8  u32 (1.6 MB)
    float*    dis   = (float*)(h2sb + (size_t)N * 8);  // N
    int*      deg   = (int*)(dis + N);                 // N
    int*      rowptr= deg + N;                         // N+1
    int*      cursor= rowptr + N + 1;                  // N
    int*      colidx= cursor + N;                      // E

    hipMemsetAsync(deg, 0, (size_t)N * sizeof(int), stream);

    deg_kernel<<<(E + 255) / 256, 256, 0, stream>>>(dst, deg, E);
    scan_kernel<<<1, 1024, 0, stream>>>(deg, rowptr, cursor, dis, N, E);
    fill_kernel<<<(E + 255) / 256, 256, 0, stream>>>(src, dst, cursor, colidx, E);

    gemm1s_kernel<<<((size_t)N * 32 + 255) / 256, 256, 0, stream>>>(x, W1, dis, h1sb, N);

    layer1_kernel<<<(N + 3) / 4, 256, 0, stream>>>(rowptr, colidx, h1sb, dis, b1, W2, h2sb, N);

    layer2_kernel<<<((size_t)N * 8 + 255) / 256, 256, 0, stream>>>(rowptr, colidx, h2sb, dis, b2, out, N);
}

// Round 6
// 458.559 us; speedup vs baseline: 3.8431x; 1.4191x over previous
//
#include <hip/hip_runtime.h>
#include <math.h>

#define NF 256
#define NH 128
#define NC 16

typedef __attribute__((ext_vector_type(8))) short bf16x8;
typedef __attribute__((ext_vector_type(4))) float f32x4;

// ---- bf16 helpers ---------------------------------------------------------
__device__ __forceinline__ unsigned f2b(float f) {            // RNE to bf16 bits
    unsigned u = __float_as_uint(f);
    return (u + 0x7FFFu + ((u >> 16) & 1u)) >> 16;
}
__device__ __forceinline__ unsigned pack2(float a, float b) { // RNE pair
    return f2b(a) | (f2b(b) << 16);
}
__device__ __forceinline__ unsigned packt(float a, float b) { // truncate pair (MFMA inputs)
    return (__float_as_uint(a) >> 16) | (__float_as_uint(b) & 0xFFFF0000u);
}
__device__ __forceinline__ float blo(unsigned u) { return __uint_as_float(u << 16); }
__device__ __forceinline__ float bhi(unsigned u) { return __uint_as_float(u & 0xFFFF0000u); }

// ---------------------------------------------------------------------------
__global__ void deg_kernel(const int* __restrict__ dst, int* __restrict__ deg, int E) {
    int e = blockIdx.x * 256 + threadIdx.x;
    if (e < E) atomicAdd(&deg[dst[e]], 1);
}

// ---------------------------------------------------------------------------
// Single-block exclusive scan of deg -> rowptr & cursor; also dis = rsqrt(deg+1).
__global__ void scan_kernel(const int* __restrict__ deg, int* __restrict__ rowptr,
                            int* __restrict__ cursor, float* __restrict__ dis,
                            int N, int E) {
    __shared__ int sm[1024];
    int tid = threadIdx.x;
    int chunk = (N + 1023) >> 10;
    int base = tid * chunk;
    int end = base + chunk; if (end > N) end = N;
    int mysum = 0;
    for (int i = base; i < end; ++i) mysum += deg[i];
    sm[tid] = mysum;
    __syncthreads();
    for (int off = 1; off < 1024; off <<= 1) {
        int v = (tid >= off) ? sm[tid - off] : 0;
        __syncthreads();
        sm[tid] += v;
        __syncthreads();
    }
    int running = sm[tid] - mysum;
    for (int i = base; i < end; ++i) {
        rowptr[i] = running;
        cursor[i] = running;
        dis[i] = rsqrtf((float)(deg[i] + 1));
        running += deg[i];
    }
    if (tid == 0) rowptr[N] = E;
}

// ---------------------------------------------------------------------------
// Bucket edges by dst (slot order nondeterministic -> only fp32 sum order).
__global__ void fill_kernel(const int* __restrict__ src, const int* __restrict__ dst,
                            int* __restrict__ cursor, int* __restrict__ colidx, int E) {
    int e = blockIdx.x * 256 + threadIdx.x;
    if (e < E) {
        int pos = atomicAdd(&cursor[dst[e]], 1);
        colidx[pos] = src[e];
    }
}

// ---------------------------------------------------------------------------
// h1 = dis * (x @ W1) via MFMA bf16, stored as bf16 (ushort row-major [N][128]).
// Block: 64 rows, 4 waves x 16 rows. W1 staged once/block into LDS as bf16
// TRANSPOSED [n=128][k=256] (64KB exactly) with XOR swizzle byte^=(n&7)<<4
// (2-way bank conflict on ds_read_b128 = free).  Per wave: 8 N-tiles x 8
// K-steps of mfma_f32_16x16x32_bf16.  W1 L2 traffic: 3.2GB -> 100MB vs old.
__global__ __launch_bounds__(256) void gemm1_mfma_kernel(
    const float* __restrict__ x, const float* __restrict__ W1,
    const float* __restrict__ dis, unsigned short* __restrict__ h1us, int N) {
    __shared__ char sW1T[65536];
    int tid = threadIdx.x;
    // stage: W1[k][n] (coalesced read) -> sW1T[n][k] bf16 RNE, swizzled
    for (int idx = tid; idx < NF * NH; idx += 256) {
        int k = idx >> 7, n = idx & 127;
        unsigned short h = (unsigned short)f2b(W1[idx]);
        *(unsigned short*)(sW1T + n * 512 + ((k * 2) ^ ((n & 7) << 4))) = h;
    }
    __syncthreads();

    int wid = tid >> 6, lane = tid & 63;
    int lrow = lane & 15, lk = lane >> 4;      // A-frag: row=lane&15, k-chunk=lane>>4
    int rb = blockIdx.x * 64 + wid * 16;
    int ra = rb + lrow;
    int rc = ra < N ? ra : N - 1;              // clamp (last block); results discarded
    const float* xr = x + (size_t)rc * NF + lk * 8;

    f32x4 acc[8];
#pragma unroll
    for (int t = 0; t < 8; ++t) acc[t] = (f32x4){0.f, 0.f, 0.f, 0.f};

#pragma unroll
    for (int kk = 0; kk < 8; ++kk) {
        float4 lo = *reinterpret_cast<const float4*>(xr + kk * 32);
        float4 hi = *reinterpret_cast<const float4*>(xr + kk * 32 + 4);
        union { unsigned u[4]; bf16x8 v; } av;
        av.u[0] = packt(lo.x, lo.y);
        av.u[1] = packt(lo.z, lo.w);
        av.u[2] = packt(hi.x, hi.y);
        av.u[3] = packt(hi.z, hi.w);
        int kbyte = kk * 64 + lk * 16;
#pragma unroll
        for (int nt = 0; nt < 8; ++nt) {
            int n = nt * 16 + lrow;            // B-frag: col=lane&15, k-chunk=lane>>4
            bf16x8 bv = *(const bf16x8*)(sW1T + n * 512 + (kbyte ^ ((n & 7) << 4)));
            acc[nt] = __builtin_amdgcn_mfma_f32_16x16x32_bf16(av.v, bv, acc[nt], 0, 0, 0);
        }
    }
    // C/D layout (verified m89): col = lane&15, row_in_tile = (lane>>4)*4 + r
    int crow0 = rb + lk * 4;
#pragma unroll
    for (int r = 0; r < 4; ++r) {
        int row = crow0 + r;
        if (row < N) {
            float dr = dis[row];
            unsigned short* orow = h1us + (size_t)row * NH + lrow;
#pragma unroll
            for (int nt = 0; nt < 8; ++nt)
                orow[nt * 16] = (unsigned short)f2b(acc[nt][r] * dr);
        }
    }
}

// ---------------------------------------------------------------------------
// Layer 1 pull + ReLU + GEMM2, fused.  One wave per node (4 nodes/block).
// Gathers bf16 rows (256B/edge); fp32 accumulate; h2sb written bf16-packed.
__global__ __launch_bounds__(256) void layer1_kernel(
    const int* __restrict__ rowptr, const int* __restrict__ colidx,
    const unsigned* __restrict__ h1sb, const float* __restrict__ dis,
    const float* __restrict__ b1, const float* __restrict__ W2,
    unsigned* __restrict__ h2sb, int N) {
    __shared__ float sW2[NH * NC];   // 8 KB
    __shared__ float srow[4][NH];    // 2 KB
    int tid = threadIdx.x;
    for (int k = tid; k < NH * NC; k += 256) sW2[k] = W2[k];
    __syncthreads();

    int wid = tid >> 6, lane = tid & 63;
    int i = blockIdx.x * 4 + wid;
    if (i >= N) return;
    int e = rowptr[i], e1 = rowptr[i + 1];
    unsigned sv = h1sb[(size_t)i * 64 + lane];          // self-loop
    float accx = blo(sv), accy = bhi(sv);
    for (; e + 4 <= e1; e += 4) {
        int a = colidx[e], b = colidx[e + 1], c = colidx[e + 2], d = colidx[e + 3];
        unsigned va = h1sb[(size_t)a * 64 + lane];
        unsigned vb = h1sb[(size_t)b * 64 + lane];
        unsigned vc = h1sb[(size_t)c * 64 + lane];
        unsigned vd = h1sb[(size_t)d * 64 + lane];
        accx += (blo(va) + blo(vb)) + (blo(vc) + blo(vd));
        accy += (bhi(va) + bhi(vb)) + (bhi(vc) + bhi(vd));
    }
    for (; e < e1; ++e) {
        unsigned v = h1sb[(size_t)colidx[e] * 64 + lane];
        accx += blo(v); accy += bhi(v);
    }
    float di = dis[i];
    int c0 = lane * 2;
    srow[wid][c0]     = fmaxf(di * accx + b1[c0], 0.f);
    srow[wid][c0 + 1] = fmaxf(di * accy + b1[c0 + 1], 0.f);
    // fused GEMM2: lane = q*16+j; partial over c in [q*32, q*32+32)
    int j = lane & 15, q = lane >> 4;
    const float* rw = srow[wid];
    float p = 0.f;
#pragma unroll
    for (int cc = 0; cc < 32; ++cc) {
        int c = q * 32 + cc;
        p += rw[c] * sW2[c * NC + j];
    }
    p += __shfl_xor(p, 16, 64);
    p += __shfl_xor(p, 32, 64);
    float dp = di * p;                       // every lane: full sum for class (lane&15)
    float plo = __shfl(dp, (lane << 1) & 63, 64);
    float phi = __shfl(dp, ((lane << 1) | 1) & 63, 64);
    if (lane < 8) h2sb[(size_t)i * 8 + lane] = pack2(plo, phi);
}

// ---------------------------------------------------------------------------
// Layer 2 pull + bias + log_softmax.  8 lanes/node (2 classes per lane).
__global__ void layer2_kernel(const int* __restrict__ rowptr, const int* __restrict__ colidx,
                              const unsigned* __restrict__ h2sb, const float* __restrict__ dis,
                              const float* __restrict__ b2, float* __restrict__ out, int N) {
    int t = blockIdx.x * 256 + threadIdx.x;
    int i = t >> 3;
    if (i >= N) return;
    int j2 = t & 7;
    int e = rowptr[i], e1 = rowptr[i + 1];
    unsigned sv = h2sb[(size_t)i * 8 + j2];             // self-loop
    float ax = blo(sv), ay = bhi(sv);
    for (; e + 4 <= e1; e += 4) {
        int a = colidx[e], b = colidx[e + 1], c = colidx[e + 2], d = colidx[e + 3];
        unsigned ga = h2sb[(size_t)a * 8 + j2];
        unsigned gb = h2sb[(size_t)b * 8 + j2];
        unsigned gc = h2sb[(size_t)c * 8 + j2];
        unsigned gd = h2sb[(size_t)d * 8 + j2];
        ax += (blo(ga) + blo(gb)) + (blo(gc) + blo(gd));
        ay += (bhi(ga) + bhi(gb)) + (bhi(gc) + bhi(gd));
    }
    for (; e < e1; ++e) {
        unsigned g = h2sb[(size_t)colidx[e] * 8 + j2];
        ax += blo(g); ay += bhi(g);
    }
    float di = dis[i];
    float l0 = di * ax + b2[2 * j2];
    float l1 = di * ay + b2[2 * j2 + 1];
    float m = fmaxf(l0, l1);
    m = fmaxf(m, __shfl_xor(m, 1, 64));
    m = fmaxf(m, __shfl_xor(m, 2, 64));
    m = fmaxf(m, __shfl_xor(m, 4, 64));
    float s = __expf(l0 - m) + __expf(l1 - m);
    s += __shfl_xor(s, 1, 64);
    s += __shfl_xor(s, 2, 64);
    s += __shfl_xor(s, 4, 64);
    float lse = m + __logf(s);
    float2 o = make_float2(l0 - lse, l1 - lse);
    *reinterpret_cast<float2*>(out + (size_t)i * NC + 2 * j2) = o;
}

// ---------------------------------------------------------------------------
extern "C" void kernel_launch(void* const* d_in, const int* in_sizes, int n_in,
                              void* d_out, int out_size, void* d_ws, size_t ws_size,
                              hipStream_t stream) {
    const float* x  = (const float*)d_in[0];
    const int*   ei = (const int*)d_in[1];
    const float* W1 = (const float*)d_in[2];
    const float* b1 = (const float*)d_in[3];
    const float* W2 = (const float*)d_in[4];
    const float* b2 = (const float*)d_in[5];
    float* out = (float*)d_out;

    const int N = in_sizes[0] / NF;   // 50000
    const int E = in_sizes[1] / 2;    // 1600000
    const int* src = ei;
    const int* dst = ei + E;

    // workspace layout (~22 MB)
    unsigned* h1sb  = (unsigned*)d_ws;                 // N*64 u32 (12.8 MB, bf16 pairs)
    unsigned* h2sb  = h1sb + (size_t)N * 64;           // N*8  u32 (1.6 MB)
    float*    dis   = (float*)(h2sb + (size_t)N * 8);  // N
    int*      deg   = (int*)(dis + N);                 // N
    int*      rowptr= deg + N;                         // N+1
    int*      cursor= rowptr + N + 1;                  // N
    int*      colidx= cursor + N;                      // E

    hipMemsetAsync(deg, 0, (size_t)N * sizeof(int), stream);

    deg_kernel<<<(E + 255) / 256, 256, 0, stream>>>(dst, deg, E);
    scan_kernel<<<1, 1024, 0, stream>>>(deg, rowptr, cursor, dis, N, E);
    fill_kernel<<<(E + 255) / 256, 256, 0, stream>>>(src, dst, cursor, colidx, E);

    gemm1_mfma_kernel<<<(N + 63) / 64, 256, 0, stream>>>(x, W1, dis,
                                                         (unsigned short*)h1sb, N);

    layer1_kernel<<<(N + 3) / 4, 256, 0, stream>>>(rowptr, colidx, h1sb, dis, b1, W2, h2sb, N);

    layer2_kernel<<<((size_t)N * 8 + 255) / 256, 256, 0, stream>>>(rowptr, colidx, h2sb, dis, b2, out, N);
}

// Round 7
// 284.596 us; speedup vs baseline: 6.1922x; 1.6113x over previous
//
#include <hip/hip_runtime.h>
#include <math.h>

#define NF 256
#define NH 128
#define NC 16
#define NPART 8
#define NCHUNK 128

typedef __attribute__((ext_vector_type(8))) short bf16x8;
typedef __attribute__((ext_vector_type(4))) float f32x4;

// ---- bf16 helpers ---------------------------------------------------------
__device__ __forceinline__ unsigned f2b(float f) {            // RNE to bf16 bits
    unsigned u = __float_as_uint(f);
    return (u + 0x7FFFu + ((u >> 16) & 1u)) >> 16;
}
__device__ __forceinline__ unsigned pack2(float a, float b) { // RNE pair
    return f2b(a) | (f2b(b) << 16);
}
__device__ __forceinline__ unsigned packt(float a, float b) { // truncate pair (MFMA inputs)
    return (__float_as_uint(a) >> 16) | (__float_as_uint(b) & 0xFFFF0000u);
}
__device__ __forceinline__ float blo(unsigned u) { return __uint_as_float(u << 16); }
__device__ __forceinline__ float bhi(unsigned u) { return __uint_as_float(u & 0xFFFF0000u); }

// ---------------------------------------------------------------------------
// Partitioned degree count: block b -> dst-range (b&7), edge-chunk (b>>3).
// Consecutive blockIdx round-robin across XCDs => each dst-partition's counter
// lines stay in ONE XCD's L2 (no cross-XCD atomic line ping-pong).
__global__ void degpart_kernel(const int* __restrict__ dst, int* __restrict__ deg,
                               int E, int N) {
    int b = blockIdx.x;
    int part = b & (NPART - 1), chunk = b >> 3;
    int psz = (N + NPART - 1) / NPART;
    int lo = part * psz;
    int hi = lo + psz; if (hi > N) hi = N;
    int e0 = (int)((long long)chunk * E / NCHUNK);
    int e1 = (int)((long long)(chunk + 1) * E / NCHUNK);
    for (int e = e0 + threadIdx.x; e < e1; e += 256) {
        int d = dst[e];
        if (d >= lo && d < hi) atomicAdd(&deg[d], 1);
    }
}

// ---------------------------------------------------------------------------
// Hierarchical scan, phase A: per-block (256-elt) sums of deg.
__global__ void scanA_kernel(const int* __restrict__ deg, int* __restrict__ bsum, int N) {
    __shared__ int sm[256];
    int tid = threadIdx.x;
    int i = blockIdx.x * 256 + tid;
    int v = (i < N) ? deg[i] : 0;
    sm[tid] = v;
    __syncthreads();
    for (int off = 128; off > 0; off >>= 1) {
        if (tid < off) sm[tid] += sm[tid + off];
        __syncthreads();
    }
    if (tid == 0) bsum[blockIdx.x] = sm[0];
}

// phase B: single small block exclusive-scans the G<=1024 block sums.
__global__ void scanB_kernel(int* __restrict__ bsum, int* __restrict__ boff,
                             int G, int E, int* __restrict__ rowptrN) {
    __shared__ int sm[1024];
    int tid = threadIdx.x;
    int v = (tid < G) ? bsum[tid] : 0;
    sm[tid] = v;
    __syncthreads();
    for (int off = 1; off < 1024; off <<= 1) {
        int t = (tid >= off) ? sm[tid - off] : 0;
        __syncthreads();
        sm[tid] += t;
        __syncthreads();
    }
    if (tid < G) boff[tid] = sm[tid] - v;   // exclusive
    if (tid == 0) *rowptrN = E;             // rowptr[N]
}

// phase C: per-block local exclusive scan + block offset; fuse dis=rsqrt(deg+1).
__global__ void scanC_kernel(const int* __restrict__ deg, const int* __restrict__ boff,
                             int* __restrict__ rowptr, int* __restrict__ cursor,
                             float* __restrict__ dis, int N) {
    __shared__ int sm[256];
    int tid = threadIdx.x;
    int i = blockIdx.x * 256 + tid;
    int v = (i < N) ? deg[i] : 0;
    sm[tid] = v;
    __syncthreads();
    for (int off = 1; off < 256; off <<= 1) {
        int t = (tid >= off) ? sm[tid - off] : 0;
        __syncthreads();
        sm[tid] += t;
        __syncthreads();
    }
    if (i < N) {
        int r = boff[blockIdx.x] + sm[tid] - v;
        rowptr[i] = r;
        cursor[i] = r;
        dis[i] = rsqrtf((float)(v + 1));
    }
}

// ---------------------------------------------------------------------------
// Partitioned bucket fill (same partition scheme as degpart): each partition's
// cursor + colidx region stays XCD-L2-resident -> writes coalesce in L2
// (WRITE_SIZE ~100MB -> ~6.4MB). Slot order nondeterministic (fp32 sum order).
__global__ void fillpart_kernel(const int* __restrict__ src, const int* __restrict__ dst,
                                int* __restrict__ cursor, int* __restrict__ colidx,
                                int E, int N) {
    int b = blockIdx.x;
    int part = b & (NPART - 1), chunk = b >> 3;
    int psz = (N + NPART - 1) / NPART;
    int lo = part * psz;
    int hi = lo + psz; if (hi > N) hi = N;
    int e0 = (int)((long long)chunk * E / NCHUNK);
    int e1 = (int)((long long)(chunk + 1) * E / NCHUNK);
    for (int e = e0 + threadIdx.x; e < e1; e += 256) {
        int d = dst[e];
        if (d >= lo && d < hi) {
            int pos = atomicAdd(&cursor[d], 1);
            colidx[pos] = src[e];
        }
    }
}

// ---------------------------------------------------------------------------
// h1 = dis * (x @ W1) via MFMA bf16, stored bf16 (ushort row-major [N][128]).
// W1 staged once/block into LDS bf16-transposed [n=128][k=256] (64KB) with
// XOR swizzle byte^=(n&7)<<4 (2-way conflict = free). 64 rows/block,
// 4 waves x 16 rows; per wave 8 N-tiles x 8 K-steps of mfma 16x16x32.
__global__ __launch_bounds__(256) void gemm1_mfma_kernel(
    const float* __restrict__ x, const float* __restrict__ W1,
    const float* __restrict__ dis, unsigned short* __restrict__ h1us, int N) {
    __shared__ char sW1T[65536];
    int tid = threadIdx.x;
    for (int idx = tid; idx < NF * NH; idx += 256) {
        int k = idx >> 7, n = idx & 127;
        unsigned short h = (unsigned short)f2b(W1[idx]);
        *(unsigned short*)(sW1T + n * 512 + ((k * 2) ^ ((n & 7) << 4))) = h;
    }
    __syncthreads();

    int wid = tid >> 6, lane = tid & 63;
    int lrow = lane & 15, lk = lane >> 4;      // A-frag: row=lane&15, k-chunk=lane>>4
    int rb = blockIdx.x * 64 + wid * 16;
    int ra = rb + lrow;
    int rc = ra < N ? ra : N - 1;              // clamp (last block); extras discarded
    const float* xr = x + (size_t)rc * NF + lk * 8;

    f32x4 acc[8];
#pragma unroll
    for (int t = 0; t < 8; ++t) acc[t] = (f32x4){0.f, 0.f, 0.f, 0.f};

#pragma unroll
    for (int kk = 0; kk < 8; ++kk) {
        float4 lo = *reinterpret_cast<const float4*>(xr + kk * 32);
        float4 hi = *reinterpret_cast<const float4*>(xr + kk * 32 + 4);
        union { unsigned u[4]; bf16x8 v; } av;
        av.u[0] = packt(lo.x, lo.y);
        av.u[1] = packt(lo.z, lo.w);
        av.u[2] = packt(hi.x, hi.y);
        av.u[3] = packt(hi.z, hi.w);
        int kbyte = kk * 64 + lk * 16;
#pragma unroll
        for (int nt = 0; nt < 8; ++nt) {
            int n = nt * 16 + lrow;            // B-frag: col=lane&15, k-chunk=lane>>4
            bf16x8 bv = *(const bf16x8*)(sW1T + n * 512 + (kbyte ^ ((n & 7) << 4)));
            acc[nt] = __builtin_amdgcn_mfma_f32_16x16x32_bf16(av.v, bv, acc[nt], 0, 0, 0);
        }
    }
    // C/D layout (verified m89): col = lane&15, row_in_tile = (lane>>4)*4 + r
    int crow0 = rb + lk * 4;
#pragma unroll
    for (int r = 0; r < 4; ++r) {
        int row = crow0 + r;
        if (row < N) {
            float dr = dis[row];
            unsigned short* orow = h1us + (size_t)row * NH + lrow;
#pragma unroll
            for (int nt = 0; nt < 8; ++nt)
                orow[nt * 16] = (unsigned short)f2b(acc[nt][r] * dr);
        }
    }
}

// ---------------------------------------------------------------------------
// Layer 1 pull + ReLU + GEMM2, fused.  One wave per node (4 nodes/block).
__global__ __launch_bounds__(256) void layer1_kernel(
    const int* __restrict__ rowptr, const int* __restrict__ colidx,
    const unsigned* __restrict__ h1sb, const float* __restrict__ dis,
    const float* __restrict__ b1, const float* __restrict__ W2,
    unsigned* __restrict__ h2sb, int N) {
    __shared__ float sW2[NH * NC];   // 8 KB
    __shared__ float srow[4][NH];    // 2 KB
    int tid = threadIdx.x;
    for (int k = tid; k < NH * NC; k += 256) sW2[k] = W2[k];
    __syncthreads();

    int wid = tid >> 6, lane = tid & 63;
    int i = blockIdx.x * 4 + wid;
    if (i >= N) return;
    int e = rowptr[i], e1 = rowptr[i + 1];
    unsigned sv = h1sb[(size_t)i * 64 + lane];          // self-loop
    float accx = blo(sv), accy = bhi(sv);
    for (; e + 4 <= e1; e += 4) {
        int a = colidx[e], b = colidx[e + 1], c = colidx[e + 2], d = colidx[e + 3];
        unsigned va = h1sb[(size_t)a * 64 + lane];
        unsigned vb = h1sb[(size_t)b * 64 + lane];
        unsigned vc = h1sb[(size_t)c * 64 + lane];
        unsigned vd = h1sb[(size_t)d * 64 + lane];
        accx += (blo(va) + blo(vb)) + (blo(vc) + blo(vd));
        accy += (bhi(va) + bhi(vb)) + (bhi(vc) + bhi(vd));
    }
    for (; e < e1; ++e) {
        unsigned v = h1sb[(size_t)colidx[e] * 64 + lane];
        accx += blo(v); accy += bhi(v);
    }
    float di = dis[i];
    int c0 = lane * 2;
    srow[wid][c0]     = fmaxf(di * accx + b1[c0], 0.f);
    srow[wid][c0 + 1] = fmaxf(di * accy + b1[c0 + 1], 0.f);
    int j = lane & 15, q = lane >> 4;
    const float* rw = srow[wid];
    float p = 0.f;
#pragma unroll
    for (int cc = 0; cc < 32; ++cc) {
        int c = q * 32 + cc;
        p += rw[c] * sW2[c * NC + j];
    }
    p += __shfl_xor(p, 16, 64);
    p += __shfl_xor(p, 32, 64);
    float dp = di * p;
    float plo = __shfl(dp, (lane << 1) & 63, 64);
    float phi = __shfl(dp, ((lane << 1) | 1) & 63, 64);
    if (lane < 8) h2sb[(size_t)i * 8 + lane] = pack2(plo, phi);
}

// ---------------------------------------------------------------------------
// Layer 2 pull + bias + log_softmax.  8 lanes/node (2 classes per lane).
__global__ void layer2_kernel(const int* __restrict__ rowptr, const int* __restrict__ colidx,
                              const unsigned* __restrict__ h2sb, const float* __restrict__ dis,
                              const float* __restrict__ b2, float* __restrict__ out, int N) {
    int t = blockIdx.x * 256 + threadIdx.x;
    int i = t >> 3;
    if (i >= N) return;
    int j2 = t & 7;
    int e = rowptr[i], e1 = rowptr[i + 1];
    unsigned sv = h2sb[(size_t)i * 8 + j2];             // self-loop
    float ax = blo(sv), ay = bhi(sv);
    for (; e + 4 <= e1; e += 4) {
        int a = colidx[e], b = colidx[e + 1], c = colidx[e + 2], d = colidx[e + 3];
        unsigned ga = h2sb[(size_t)a * 8 + j2];
        unsigned gb = h2sb[(size_t)b * 8 + j2];
        unsigned gc = h2sb[(size_t)c * 8 + j2];
        unsigned gd = h2sb[(size_t)d * 8 + j2];
        ax += (blo(ga) + blo(gb)) + (blo(gc) + blo(gd));
        ay += (bhi(ga) + bhi(gb)) + (bhi(gc) + bhi(gd));
    }
    for (; e < e1; ++e) {
        unsigned g = h2sb[(size_t)colidx[e] * 8 + j2];
        ax += blo(g); ay += bhi(g);
    }
    float di = dis[i];
    float l0 = di * ax + b2[2 * j2];
    float l1 = di * ay + b2[2 * j2 + 1];
    float m = fmaxf(l0, l1);
    m = fmaxf(m, __shfl_xor(m, 1, 64));
    m = fmaxf(m, __shfl_xor(m, 2, 64));
    m = fmaxf(m, __shfl_xor(m, 4, 64));
    float s = __expf(l0 - m) + __expf(l1 - m);
    s += __shfl_xor(s, 1, 64);
    s += __shfl_xor(s, 2, 64);
    s += __shfl_xor(s, 4, 64);
    float lse = m + __logf(s);
    float2 o = make_float2(l0 - lse, l1 - lse);
    *reinterpret_cast<float2*>(out + (size_t)i * NC + 2 * j2) = o;
}

// ---------------------------------------------------------------------------
extern "C" void kernel_launch(void* const* d_in, const int* in_sizes, int n_in,
                              void* d_out, int out_size, void* d_ws, size_t ws_size,
                              hipStream_t stream) {
    const float* x  = (const float*)d_in[0];
    const int*   ei = (const int*)d_in[1];
    const float* W1 = (const float*)d_in[2];
    const float* b1 = (const float*)d_in[3];
    const float* W2 = (const float*)d_in[4];
    const float* b2 = (const float*)d_in[5];
    float* out = (float*)d_out;

    const int N = in_sizes[0] / NF;   // 50000
    const int E = in_sizes[1] / 2;    // 1600000
    const int* src = ei;
    const int* dst = ei + E;
    const int G = (N + 255) / 256;    // scan blocks (196)

    // workspace layout (~22 MB)
    unsigned* h1sb  = (unsigned*)d_ws;                 // N*64 u32 (12.8 MB, bf16 pairs)
    unsigned* h2sb  = h1sb + (size_t)N * 64;           // N*8  u32 (1.6 MB)
    float*    dis   = (float*)(h2sb + (size_t)N * 8);  // N
    int*      deg   = (int*)(dis + N);                 // N
    int*      rowptr= deg + N;                         // N+1
    int*      cursor= rowptr + N + 1;                  // N
    int*      bsum  = cursor + N;                      // G
    int*      boff  = bsum + 1024;                     // G
    int*      colidx= boff + 1024;                     // E

    hipMemsetAsync(deg, 0, (size_t)N * sizeof(int), stream);

    degpart_kernel<<<NPART * NCHUNK, 256, 0, stream>>>(dst, deg, E, N);

    scanA_kernel<<<G, 256, 0, stream>>>(deg, bsum, N);
    scanB_kernel<<<1, 1024, 0, stream>>>(bsum, boff, G, E, rowptr + N);
    scanC_kernel<<<G, 256, 0, stream>>>(deg, boff, rowptr, cursor, dis, N);

    fillpart_kernel<<<NPART * NCHUNK, 256, 0, stream>>>(src, dst, cursor, colidx, E, N);

    gemm1_mfma_kernel<<<(N + 63) / 64, 256, 0, stream>>>(x, W1, dis,
                                                         (unsigned short*)h1sb, N);

    layer1_kernel<<<(N + 3) / 4, 256, 0, stream>>>(rowptr, colidx, h1sb, dis, b1, W2, h2sb, N);

    layer2_kernel<<<((size_t)N * 8 + 255) / 256, 256, 0, stream>>>(rowptr, colidx, h2sb, dis, b2, out, N);
}